// Round 9
// baseline (2953.456 us; speedup 1.0000x reference)
//
#include <hip/hip_runtime.h>

#define T_ 1024
#define I_ 18
#define NCH 64           // batch chunks of 16 rows
#define GUARD (1 << 18)

typedef _Float16 f16;
typedef _Float16 f16x8 __attribute__((ext_vector_type(8)));
typedef _Float16 f16x4 __attribute__((ext_vector_type(4)));
typedef float f32x4 __attribute__((ext_vector_type(4)));

#define MFMA16(a, b, c) __builtin_amdgcn_mfma_f32_16x16x32_f16((a), (b), (c), 0, 0, 0)
#define SB() __builtin_amdgcn_sched_barrier(0)

// ---- ws layout (f16 units unless noted) ----
// hb0: [slot4][chunk64][kt8][512]   = 2MB   (h0 A-fragments)
// gb1: [slot4][chunk64][nt48][256]  = 6MB   (gi1 pre-activations, C-layout)
// flags int[NCH*32]: [c][grp4][w8]  grp: 0=fh0 1=fgi 2=fg1p 3=fh1p
#define HB0_ELEMS (4 * 64 * 4096)
#define GB1_ELEMS (4 * 64 * 12288)
#define NFLAGS (NCH * 32)
// LDS (dynamic, 114688 B): wlds f16[96*512] (kt 6,7 of W) | hring f16[2*4096]
#define LDS_BYTES 114688

__global__ void init_ws(int* __restrict__ flg) {
  int i = blockIdx.x * blockDim.x + threadIdx.x;
  if (i < NFLAGS + 192 + 1) flg[i] = 0;  // flags | ids | dec
}

__device__ __forceinline__ float sigm(float v) {
  return __builtin_amdgcn_rcpf(1.f + __expf(-v));
}
__device__ __forceinline__ float tanh_fast(float v) {
  v = fmaxf(v, -15.f);
  float e = __expf(-2.f * v);
  return (1.f - e) * __builtin_amdgcn_rcpf(1.f + e);
}
__device__ __forceinline__ f16x8 cvt8(const float* q) {
  const f32x4* a = (const f32x4*)q;
  f32x4 u = a[0], v = a[1];
  f16x8 r;
  r[0] = (f16)u[0]; r[1] = (f16)u[1]; r[2] = (f16)u[2]; r[3] = (f16)u[3];
  r[4] = (f16)v[0]; r[5] = (f16)v[1]; r[6] = (f16)v[2]; r[7] = (f16)v[3];
  return r;
}

// FAST = XCD-local L2 (plain stores, nt loads). slow = sc0 sc1 MALL-coherent.
template <bool FAST>
__device__ __forceinline__ f16x8 ldh(const f16* p) {
  f16x8 r;
  if (FAST) asm volatile("global_load_dwordx4 %0, %1, off nt" : "=&v"(r) : "v"(p));
  else asm volatile("global_load_dwordx4 %0, %1, off sc0 sc1" : "=&v"(r) : "v"(p));
  return r;
}
template <bool FAST>
__device__ __forceinline__ f16x4 ldg8(const f16* p) {
  f16x4 r;
  if (FAST) asm volatile("global_load_dwordx2 %0, %1, off nt" : "=&v"(r) : "v"(p));
  else asm volatile("global_load_dwordx2 %0, %1, off sc0 sc1" : "=&v"(r) : "v"(p));
  return r;
}
template <bool FAST>
__device__ __forceinline__ void stg16(f16* p, f16x8 v) {
  if (FAST) asm volatile("global_store_dwordx4 %0, %1, off" ::"v"(p), "v"(v) : "memory");
  else asm volatile("global_store_dwordx4 %0, %1, off sc0 sc1" ::"v"(p), "v"(v) : "memory");
}
template <bool FAST>
__device__ __forceinline__ void stg8(f16* p, f16x4 v) {
  if (FAST) asm volatile("global_store_dwordx2 %0, %1, off" ::"v"(p), "v"(v) : "memory");
  else asm volatile("global_store_dwordx2 %0, %1, off sc0 sc1" ::"v"(p), "v"(v) : "memory");
}
template <bool FAST>
__device__ __forceinline__ void stf(int* p, int v) {
  if (FAST) asm volatile("global_store_dword %0, %1, off" ::"v"(p), "v"(v) : "memory");
  else asm volatile("global_store_dword %0, %1, off sc0 sc1" ::"v"(p), "v"(v) : "memory");
}
template <bool FAST>
__device__ __forceinline__ int ldf(const int* p) {  // flag load + drain
  int r;
  if (FAST)
    asm volatile("global_load_dword %0, %1, off nt\n\ts_waitcnt vmcnt(0)"
                 : "=&v"(r) : "v"(p) : "memory");
  else
    asm volatile("global_load_dword %0, %1, off sc0 sc1\n\ts_waitcnt vmcnt(0)"
                 : "=&v"(r) : "v"(p) : "memory");
  return r;
}
template <bool FAST>
__device__ __forceinline__ void ldf_nw(const int* p, int* dst) {  // no wait
  if (FAST) asm volatile("global_load_dword %0, %1, off nt" : "=&v"(*dst) : "v"(p) : "memory");
  else asm volatile("global_load_dword %0, %1, off sc0 sc1" : "=&v"(*dst) : "v"(p) : "memory");
}
__device__ __forceinline__ int ld_sys(const int* p) {
  int r;
  asm volatile("global_load_dword %0, %1, off sc0 sc1\n\ts_waitcnt vmcnt(0)"
               : "=&v"(r) : "v"(p) : "memory");
  return r;
}
__device__ __forceinline__ void st_sys(int* p, int v) { stf<false>(p, v); }
__device__ __forceinline__ f32x4 ldx4(const float* p) {
  f32x4 r;
  asm volatile("global_load_dwordx4 %0, %1, off" : "=&v"(r) : "v"(p));
  return r;
}

// 192 blocks x 512 threads. stage = bx/64 (0:L0 1:GI1 2:HH1), chunk c = bx%64.
// Wave w owns ntiles {g*16 + 2w + tt} (gates aligned) -> h-cols [32w, 32w+32).
// Recurrences (h0 in L0, h1 in HH1) are intra-block via LDS ring-2 +
// one __syncthreads per step. Cross-block: FIFO rings (4) with credit flags.
__global__ __launch_bounds__(512, 1) void gru_main(
    const float* __restrict__ x, const float* __restrict__ Wih0,
    const float* __restrict__ Whh0, const float* __restrict__ Wih1,
    const float* __restrict__ Whh1, const float* __restrict__ bih0,
    const float* __restrict__ bhh0, const float* __restrict__ bih1,
    const float* __restrict__ bhh1, const float* __restrict__ fcw,
    const float* __restrict__ fcb, f16* __restrict__ hb0,
    f16* __restrict__ gb1, int* __restrict__ flags, int* __restrict__ ids,
    int* __restrict__ dec, float* __restrict__ out) {
  extern __shared__ f16 lds[];  // wlds[96*512] | hring[2*4096]
  f16* hring = lds + 96 * 512;

  const int tid = threadIdx.x;
  const int wv = tid >> 6, lane = tid & 63;
  const int lrow = lane & 15, lgrp = lane >> 4;
  const int stage = blockIdx.x >> 6;  // 0,1,2
  const int c = blockIdx.x & 63;

  const float* Wm = (stage == 0) ? Whh0 : (stage == 1) ? Wih1 : Whh1;

  // ---- LDS: W kt 6,7 (96 frags) ----
  for (int idx = tid; idx < 96 * 64; idx += 512) {
    int f = idx >> 6, lf = idx & 63;
    int nt = f >> 1, kk = 6 + (f & 1);
    *(f16x8*)&lds[f * 512 + lf * 8] =
        cvt8(&Wm[(nt * 16 + (lf & 15)) * 256 + kk * 32 + (lf >> 4) * 8]);
  }
  // ---- LDS: zero h-ring (stages 0,2) ----
  for (int idx = tid; idx < 2 * 4096; idx += 512) hring[idx] = (f16)0.f;

  // ---- reg W frags kt 0..5: wfr[(g*2+tt)*6 + kt] ----
  f16x8 wfr[36];
#pragma unroll
  for (int g = 0; g < 3; ++g)
#pragma unroll
    for (int tt = 0; tt < 2; ++tt) {
      int row = g * 256 + 32 * wv + 16 * tt + lrow;
#pragma unroll
      for (int kt = 0; kt < 6; ++kt)
        wfr[(g * 2 + tt) * 6 + kt] = cvt8(&Wm[row * 256 + kt * 32 + lgrp * 8]);
    }

  // ---- XCD placement verification -> global fast/slow decision ----
  {
    unsigned xcc;
    asm volatile("s_getreg_b32 %0, hwreg(HW_REG_XCC_ID)" : "=s"(xcc));
    if (tid == 0) st_sys(ids + blockIdx.x, (int)xcc + 1);
    if (blockIdx.x == 0 && wv == 0) {
      int ok, guard = 0;
      for (;;) {
        int v0 = ld_sys(ids + lane), v1 = ld_sys(ids + 64 + lane);
        int v2 = ld_sys(ids + 128 + lane);
        ok = (v0 && v1 && v2);
        if (__all(ok)) { ok = 1; break; }
        if (++guard > (1 << 16)) { ok = 0; break; }
        __builtin_amdgcn_s_sleep(8);
      }
      int verdict = 1;
      if (ok) {
        int r0 = ld_sys(ids + lane), r1 = ld_sys(ids + 64 + lane);
        int r2 = ld_sys(ids + 128 + lane);
        int eq = (r1 == r0) && (r2 == r0);
        verdict = __all(eq) ? 2 : 1;
      }
      if (lane == 0) st_sys(dec, verdict);
    }
  }
  int decision = 1;
  {
    int g = 0;
    for (;;) {
      int d = ld_sys(dec);
      if (d) { decision = d; break; }
      if (++g > (1 << 20)) break;
      __builtin_amdgcn_s_sleep(8);
    }
  }
  __syncthreads();  // LDS weights + ring zeros visible

  int dead = 0;

  if (stage == 0) {
    // ============================ L0 ============================
    f16x8 wx[6];  // W_ih0 frags (K=18 pad 32)
#pragma unroll
    for (int g = 0; g < 3; ++g)
#pragma unroll
      for (int tt = 0; tt < 2; ++tt) {
        int row = g * 256 + 32 * wv + 16 * tt + lrow;
        f16 v[8];
#pragma unroll
        for (int j = 0; j < 8; ++j) {
          int k = lgrp * 8 + j;
          v[j] = (k < I_) ? (f16)Wih0[row * I_ + k] : (f16)0.f;
        }
        wx[g * 2 + tt] = *(f16x8*)v;
      }
    float bR[2], bZ[2], bI[2], bH[2];
#pragma unroll
    for (int tt = 0; tt < 2; ++tt) {
      int col = 32 * wv + 16 * tt + lrow;
      bR[tt] = bih0[col] + bhh0[col];
      bZ[tt] = bih0[256 + col] + bhh0[256 + col];
      bI[tt] = bih0[512 + col];
      bH[tt] = bhh0[512 + col];
    }
    float h0r[2][4] = {{0.f, 0.f, 0.f, 0.f}, {0.f, 0.f, 0.f, 0.f}};
    const float* xrow = x + (size_t)(c * 16 + lrow) * T_ * I_;
    const int o1 = (lgrp == 0) ? 0 : (lgrp == 1) ? 8 : (lgrp == 2) ? 14 : 0;
    const int o2 = (lgrp == 0) ? 4 : (lgrp == 1) ? 12 : 0;
    int* fpost = flags + c * 32 + 0 * 8 + wv;          // fh0
    const int* fcred = flags + c * 32 + 2 * 8 + (lane & 7);  // fg1p
    int cval = 0;

    auto loop0 = [&](auto FC) {
      constexpr bool F = decltype(FC)::value;
      f32x4 xA1 = ldx4(xrow + o1);
      f32x4 xA2 = ldx4(xrow + o2);
      for (int t = 0; t < T_; ++t) {
        // x(t) home (oldest 2 of outstanding); fh0/cred stay in flight
        asm volatile("s_waitcnt vmcnt(2)" ::: "memory");
        SB();
        f16x8 ax;
        {
          float s0 = (lgrp == 2) ? xA1[2] : xA1[0];
          float s1 = (lgrp == 2) ? xA1[3] : xA1[1];
          ax[0] = (f16)s0;     ax[1] = (f16)s1;
          ax[2] = (f16)xA1[2]; ax[3] = (f16)xA1[3];
          ax[4] = (f16)xA2[0]; ax[5] = (f16)xA2[1];
          ax[6] = (f16)xA2[2]; ax[7] = (f16)xA2[3];
        }
        f32x4 aR[2], aZ[2], aI[2], aH[2];
#pragma unroll
        for (int tt = 0; tt < 2; ++tt) {
          aR[tt] = (f32x4){bR[tt], bR[tt], bR[tt], bR[tt]};
          aZ[tt] = (f32x4){bZ[tt], bZ[tt], bZ[tt], bZ[tt]};
          aI[tt] = (f32x4){bI[tt], bI[tt], bI[tt], bI[tt]};
          aH[tt] = (f32x4){bH[tt], bH[tt], bH[tt], bH[tt]};
          aR[tt] = MFMA16(ax, wx[0 * 2 + tt], aR[tt]);
          aZ[tt] = MFMA16(ax, wx[1 * 2 + tt], aZ[tt]);
          aI[tt] = MFMA16(ax, wx[2 * 2 + tt], aI[tt]);
        }
        const f16* ha = &hring[((t + 1) & 1) * 4096 + lane * 8];
#pragma unroll
        for (int kt = 0; kt < 8; ++kt) {
          f16x8 a = *(const f16x8*)(ha + kt * 512);
#pragma unroll
          for (int tt = 0; tt < 2; ++tt) {
            f16x8 br = (kt < 6) ? wfr[(0 * 2 + tt) * 6 + kt]
                : *(const f16x8*)&lds[(((0 * 16 + wv * 2 + tt) * 2) + (kt - 6)) * 512 + lane * 8];
            f16x8 bz = (kt < 6) ? wfr[(1 * 2 + tt) * 6 + kt]
                : *(const f16x8*)&lds[(((1 * 16 + wv * 2 + tt) * 2) + (kt - 6)) * 512 + lane * 8];
            f16x8 bn = (kt < 6) ? wfr[(2 * 2 + tt) * 6 + kt]
                : *(const f16x8*)&lds[(((2 * 16 + wv * 2 + tt) * 2) + (kt - 6)) * 512 + lane * 8];
            aR[tt] = MFMA16(a, br, aR[tt]);
            aZ[tt] = MFMA16(a, bz, aZ[tt]);
            aH[tt] = MFMA16(a, bn, aH[tt]);
          }
        }
        // update + LDS ring write (slot t&1)
#pragma unroll
        for (int tt = 0; tt < 2; ++tt)
#pragma unroll
          for (int i = 0; i < 4; ++i) {
            float rr = sigm(aR[tt][i]);
            float zz = sigm(aZ[tt][i]);
            float nn = tanh_fast(aI[tt][i] + rr * aH[tt][i]);
            h0r[tt][i] = (1.f - zz) * nn + zz * h0r[tt][i];
            int off = wv * 512 + ((lgrp * 4 + i) + 16 * (2 * tt + (lrow >> 3))) * 8 + (lrow & 7);
            hring[(t & 1) * 4096 + off] = (f16)h0r[tt][i];
          }
        // read back own frag (kt=wv, own wave's writes only)
        f16x8 own = *(const f16x8*)&hring[(t & 1) * 4096 + wv * 512 + lane * 8];
        // credit: GI1 must have consumed slot t-4 (fg1p >= t-3)
        asm volatile("s_waitcnt vmcnt(0)" ::: "memory");  // cred/fh0 old -> free
        SB();
        if (t >= 4 && !dead) {
          if (!__all(cval >= t - 3)) {
            int guard = 0;
            for (;;) {
              int v = ldf<F>(fcred);
              if (__all(v >= t - 3)) break;
              if (++guard > GUARD) { dead = 1; break; }
            }
          }
        }
        // publish + next-x prefetch; barrier overlaps store ack
        stg16<F>(hb0 + (size_t)(((t & 3) * 64 + c) * 8 + wv) * 512 + lane * 8, own);
        {
          int tn = (t + 1 < T_) ? t + 1 : T_ - 1;
          xA1 = ldx4(xrow + (size_t)tn * I_ + o1);
          xA2 = ldx4(xrow + (size_t)tn * I_ + o2);
        }
        __syncthreads();
        asm volatile("s_waitcnt vmcnt(2)" ::: "memory");  // store ack'd, x flying
        SB();
        if (lane == 0) stf<F>(fpost, t + 1);
        ldf_nw<F>(fcred, &cval);  // preload credit for next step
      }
    };
    if (decision == 2) loop0(std::integral_constant<bool, true>{});
    else loop0(std::integral_constant<bool, false>{});
  } else if (stage == 1) {
    // ============================ GI1 ============================
    float bR[2], bZ[2], bI[2];
#pragma unroll
    for (int tt = 0; tt < 2; ++tt) {
      int col = 32 * wv + 16 * tt + lrow;
      bR[tt] = bih1[col];
      bZ[tt] = bih1[256 + col];
      bI[tt] = bih1[512 + col];
    }
    const int* fh0p = flags + c * 32 + 0 * 8 + (lane & 7);
    const int* fcred = flags + c * 32 + 3 * 8 + (lane & 7);  // fh1p
    int* fpost_p = flags + c * 32 + 2 * 8 + wv;              // fg1p
    int* fpost_d = flags + c * 32 + 1 * 8 + wv;              // fgi

    auto loop1 = [&](auto FC) {
      constexpr bool F = decltype(FC)::value;
      for (int t = 0; t < T_; ++t) {
        if (t >= 4 && !dead) {  // gi1 ring credit
          int guard = 0;
          for (;;) {
            int v = ldf<F>(fcred);
            if (__all(v >= t - 3)) break;
            if (++guard > GUARD) { dead = 1; break; }
          }
        }
        if (!dead) {  // h0(t) ready?
          int guard = 0;
          for (;;) {
            int v = ldf<F>(fh0p);
            if (__all(v >= t + 1)) break;
            if (++guard > GUARD) { dead = 1; break; }
          }
        }
        SB();
        const f16* hb = hb0 + (size_t)((t & 3) * 64 + c) * 4096 + lane * 8;
        f16x8 ah[8];
#pragma unroll
        for (int kt = 0; kt < 8; ++kt) ah[kt] = ldh<F>(hb + kt * 512);
        SB();
        f32x4 aR[2], aZ[2], aI[2];
#pragma unroll
        for (int tt = 0; tt < 2; ++tt) {
          aR[tt] = (f32x4){bR[tt], bR[tt], bR[tt], bR[tt]};
          aZ[tt] = (f32x4){bZ[tt], bZ[tt], bZ[tt], bZ[tt]};
          aI[tt] = (f32x4){bI[tt], bI[tt], bI[tt], bI[tt]};
        }
        asm volatile("s_waitcnt vmcnt(4)" ::: "memory");
        SB();
#pragma unroll
        for (int kt = 0; kt < 4; ++kt)
#pragma unroll
          for (int tt = 0; tt < 2; ++tt) {
            f16x8 br = (kt < 6) ? wfr[(0 * 2 + tt) * 6 + kt] : ah[0];
            aR[tt] = MFMA16(ah[kt], wfr[(0 * 2 + tt) * 6 + kt], aR[tt]);
            aZ[tt] = MFMA16(ah[kt], wfr[(1 * 2 + tt) * 6 + kt], aZ[tt]);
            aI[tt] = MFMA16(ah[kt], wfr[(2 * 2 + tt) * 6 + kt], aI[tt]);
            (void)br;
          }
        asm volatile("s_waitcnt vmcnt(0)" ::: "memory");
        SB();
        if (lane == 0) stf<F>(fpost_p, t + 1);  // h0(t) consumed
#pragma unroll
        for (int kt = 4; kt < 8; ++kt)
#pragma unroll
          for (int tt = 0; tt < 2; ++tt) {
            f16x8 br = (kt < 6) ? wfr[(0 * 2 + tt) * 6 + kt]
                : *(const f16x8*)&lds[(((0 * 16 + wv * 2 + tt) * 2) + (kt - 6)) * 512 + lane * 8];
            f16x8 bz = (kt < 6) ? wfr[(1 * 2 + tt) * 6 + kt]
                : *(const f16x8*)&lds[(((1 * 16 + wv * 2 + tt) * 2) + (kt - 6)) * 512 + lane * 8];
            f16x8 bn = (kt < 6) ? wfr[(2 * 2 + tt) * 6 + kt]
                : *(const f16x8*)&lds[(((2 * 16 + wv * 2 + tt) * 2) + (kt - 6)) * 512 + lane * 8];
            aR[tt] = MFMA16(ah[kt], br, aR[tt]);
            aZ[tt] = MFMA16(ah[kt], bz, aZ[tt]);
            aI[tt] = MFMA16(ah[kt], bn, aI[tt]);
          }
        // store gi1 (f16, C-layout) for 6 ntiles
        f16* gbase = gb1 + (size_t)((t & 3) * 64 + c) * 12288 + lane * 4;
#pragma unroll
        for (int g = 0; g < 3; ++g)
#pragma unroll
          for (int tt = 0; tt < 2; ++tt) {
            int nt = g * 16 + wv * 2 + tt;
            f32x4 a = (g == 0) ? aR[tt] : (g == 1) ? aZ[tt] : aI[tt];
            f16x4 v;
            v[0] = (f16)a[0]; v[1] = (f16)a[1]; v[2] = (f16)a[2]; v[3] = (f16)a[3];
            stg8<F>(gbase + nt * 256, v);
          }
        asm volatile("s_waitcnt vmcnt(0)" ::: "memory");
        SB();
        if (lane == 0) stf<F>(fpost_d, t + 1);
      }
    };
    if (decision == 2) loop1(std::integral_constant<bool, true>{});
    else loop1(std::integral_constant<bool, false>{});
  } else {
    // ============================ HH1 ============================
    float bR[2], bZ[2], bH[2];
#pragma unroll
    for (int tt = 0; tt < 2; ++tt) {
      int col = 32 * wv + 16 * tt + lrow;
      bR[tt] = bhh1[col];
      bZ[tt] = bhh1[256 + col];
      bH[tt] = bhh1[512 + col];
    }
    float h1r[2][4] = {{0.f, 0.f, 0.f, 0.f}, {0.f, 0.f, 0.f, 0.f}};
    const int* fgip = flags + c * 32 + 1 * 8 + (lane & 7);
    int* fpost = flags + c * 32 + 3 * 8 + wv;  // fh1p

    auto loop2 = [&](auto FC) {
      constexpr bool F = decltype(FC)::value;
      for (int t = 0; t < T_; ++t) {
        if (!dead) {  // gi1(t) ready?
          int guard = 0;
          for (;;) {
            int v = ldf<F>(fgip);
            if (__all(v >= t + 1)) break;
            if (++guard > GUARD) { dead = 1; break; }
          }
        }
        SB();
        const f16* gbase = gb1 + (size_t)((t & 3) * 64 + c) * 12288 + lane * 4;
        f16x4 gi[6];
#pragma unroll
        for (int g = 0; g < 3; ++g)
#pragma unroll
          for (int tt = 0; tt < 2; ++tt)
            gi[g * 2 + tt] = ldg8<F>(gbase + (g * 16 + wv * 2 + tt) * 256);
        SB();
        f32x4 aR[2], aZ[2], aH[2];
#pragma unroll
        for (int tt = 0; tt < 2; ++tt) {
          aR[tt] = (f32x4){bR[tt], bR[tt], bR[tt], bR[tt]};
          aZ[tt] = (f32x4){bZ[tt], bZ[tt], bZ[tt], bZ[tt]};
          aH[tt] = (f32x4){bH[tt], bH[tt], bH[tt], bH[tt]};
        }
        const f16* ha = &hring[((t + 1) & 1) * 4096 + lane * 8];
#pragma unroll
        for (int kt = 0; kt < 8; ++kt) {
          f16x8 a = *(const f16x8*)(ha + kt * 512);
#pragma unroll
          for (int tt = 0; tt < 2; ++tt) {
            f16x8 br = (kt < 6) ? wfr[(0 * 2 + tt) * 6 + kt]
                : *(const f16x8*)&lds[(((0 * 16 + wv * 2 + tt) * 2) + (kt - 6)) * 512 + lane * 8];
            f16x8 bz = (kt < 6) ? wfr[(1 * 2 + tt) * 6 + kt]
                : *(const f16x8*)&lds[(((1 * 16 + wv * 2 + tt) * 2) + (kt - 6)) * 512 + lane * 8];
            f16x8 bn = (kt < 6) ? wfr[(2 * 2 + tt) * 6 + kt]
                : *(const f16x8*)&lds[(((2 * 16 + wv * 2 + tt) * 2) + (kt - 6)) * 512 + lane * 8];
            aR[tt] = MFMA16(a, br, aR[tt]);
            aZ[tt] = MFMA16(a, bz, aZ[tt]);
            aH[tt] = MFMA16(a, bn, aH[tt]);
          }
        }
        asm volatile("s_waitcnt vmcnt(0)" ::: "memory");  // gi landed under MFMAs
        SB();
        if (lane == 0) stf<F>(fpost, t + 1);  // gi1(t) consumed
#pragma unroll
        for (int tt = 0; tt < 2; ++tt)
#pragma unroll
          for (int i = 0; i < 4; ++i) {
            float rr = sigm((float)gi[0 * 2 + tt][i] + aR[tt][i]);
            float zz = sigm((float)gi[1 * 2 + tt][i] + aZ[tt][i]);
            float nn = tanh_fast((float)gi[2 * 2 + tt][i] + rr * aH[tt][i]);
            h1r[tt][i] = (1.f - zz) * nn + zz * h1r[tt][i];
            int off = wv * 512 + ((lgrp * 4 + i) + 16 * (2 * tt + (lrow >> 3))) * 8 + (lrow & 7);
            hring[(t & 1) * 4096 + off] = (f16)h1r[tt][i];
          }
        __syncthreads();
      }
    };
    if (decision == 2) loop2(std::integral_constant<bool, true>{});
    else loop2(std::integral_constant<bool, false>{});

    // ---- fc head (block-local) ----
    float fw0 = fcw[32 * wv + lrow], fw1 = fcw[32 * wv + 16 + lrow];
    float* red = (float*)lds;  // reuse weight LDS (loop done, barrier below)
    __syncthreads();
#pragma unroll
    for (int i = 0; i < 4; ++i) {
      float v = h1r[0][i] * fw0 + h1r[1][i] * fw1;
#pragma unroll
      for (int m = 1; m < 16; m <<= 1) v += __shfl_xor(v, m);
      if (lrow == 0) red[wv * 16 + lgrp * 4 + i] = v;
    }
    __syncthreads();
    if (tid < 16) {
      float s = fcb[0];
#pragma unroll
      for (int w2 = 0; w2 < 8; ++w2) s += red[w2 * 16 + tid];
      out[c * 16 + tid] = s;
    }
  }
}

extern "C" void kernel_launch(void* const* d_in, const int* in_sizes, int n_in,
                              void* d_out, int out_size, void* d_ws, size_t ws_size,
                              hipStream_t stream) {
  const float* x    = (const float*)d_in[0];
  const float* Wih0 = (const float*)d_in[1];
  const float* Whh0 = (const float*)d_in[2];
  const float* bih0 = (const float*)d_in[3];
  const float* bhh0 = (const float*)d_in[4];
  const float* Wih1 = (const float*)d_in[5];
  const float* Whh1 = (const float*)d_in[6];
  const float* bih1 = (const float*)d_in[7];
  const float* bhh1 = (const float*)d_in[8];
  const float* fcw  = (const float*)d_in[9];
  const float* fcb  = (const float*)d_in[10];

  f16* hb0 = (f16*)d_ws;
  f16* gb1 = hb0 + (size_t)HB0_ELEMS;
  int* flags = (int*)(gb1 + (size_t)GB1_ELEMS);
  int* ids = flags + NFLAGS;
  int* dec = ids + 192;

  hipFuncSetAttribute((const void*)gru_main,
                      hipFuncAttributeMaxDynamicSharedMemorySize, LDS_BYTES);

  init_ws<<<16, 256, 0, stream>>>(flags);
  gru_main<<<192, 512, LDS_BYTES, stream>>>(
      x, Wih0, Whh0, Wih1, Whh1, bih0, bhh0, bih1, bhh1, fcw, fcb, hb0, gb1,
      flags, ids, dec, (float*)d_out);
}